// Round 1
// 95.220 us; speedup vs baseline: 1.0372x; 1.0372x over previous
//
#include <hip/hip_runtime.h>

// CenterLoss: loss = mean_b( ||feat[b] - centers[label[b]]|| / count[label[b]] )
// feat: [16384, 512] f32, label: [16384] i32, centers: [10000, 512] f32 -> scalar f32
//
// Measured-window theory: ~84 us of the ~98.8 us is two 256-MiB harness poison
// fills (rocprof: fillBufferAligned 2x42.2us, WRITE_SIZE=256MiB). Our slice is
// ~14 us; this version targets its latency-bound dist kernel.
//
// 2 dispatches:
//  K1: bin-ownership histogram (no global pre-zero), int4 label loads, zeroes d_out
//  K2: 512 blocks x 8 waves (4 waves/SIMD TLP, 2x previous), each wave owns 4
//      samples in a single fully-unrolled shot: 16 float4 loads in flight (ILP-4),
//      then 4 interleaved 64-lane butterflies. SGPR sample base via readfirstlane
//      -> s_load labels/counts, SGPR global bases for the vector loads.
//      Inputs are LLC-resident after harness restore — do NOT bypass cache.

constexpr int NUM_CLASSES = 10000;
constexpr int FEATURE_DIM = 512;
constexpr int BATCH       = 16384;

constexpr int HIST_BLOCKS    = 40;
constexpr int BINS_PER_BLOCK = NUM_CLASSES / HIST_BLOCKS;  // 250

constexpr int DIST_THREADS      = 512;                       // 8 waves
constexpr int WAVES_PER_BLOCK   = DIST_THREADS / 64;         // 8
constexpr int SAMPLES_PER_WAVE  = 4;                         // single-shot ILP-4
constexpr int SAMPLES_PER_BLOCK = WAVES_PER_BLOCK * SAMPLES_PER_WAVE;  // 32
constexpr int DIST_BLOCKS       = BATCH / SAMPLES_PER_BLOCK;           // 512

typedef float vfloat4 __attribute__((ext_vector_type(4)));
typedef int   vint4   __attribute__((ext_vector_type(4)));

__global__ __launch_bounds__(1024) void center_hist_kernel(const int* __restrict__ label,
                                                           int* __restrict__ count,
                                                           float* __restrict__ out) {
    __shared__ int h[BINS_PER_BLOCK];
    const int lo = blockIdx.x * BINS_PER_BLOCK;

    for (int i = threadIdx.x; i < BINS_PER_BLOCK; i += 1024) h[i] = 0;
    __syncthreads();

    // Each block scans all labels (64 KiB, L2-broadcast) as int4: 4 iterations.
    const vint4* lab4 = reinterpret_cast<const vint4*>(label);
    for (int i = threadIdx.x; i < BATCH / 4; i += 1024) {
        const vint4 l = lab4[i];
        int a;
        a = l.x - lo; if ((unsigned)a < (unsigned)BINS_PER_BLOCK) atomicAdd(&h[a], 1);
        a = l.y - lo; if ((unsigned)a < (unsigned)BINS_PER_BLOCK) atomicAdd(&h[a], 1);
        a = l.z - lo; if ((unsigned)a < (unsigned)BINS_PER_BLOCK) atomicAdd(&h[a], 1);
        a = l.w - lo; if ((unsigned)a < (unsigned)BINS_PER_BLOCK) atomicAdd(&h[a], 1);
    }
    __syncthreads();

    for (int i = threadIdx.x; i < BINS_PER_BLOCK; i += 1024) count[lo + i] = h[i];

    if (blockIdx.x == 0 && threadIdx.x == 0) out[0] = 0.0f;  // K2 accumulates on top
}

__device__ __forceinline__ float sq8(vfloat4 fa, vfloat4 fb, vfloat4 ca, vfloat4 cb) {
    vfloat4 da = fa - ca, db = fb - cb;
    return da.x*da.x + da.y*da.y + da.z*da.z + da.w*da.w
         + db.x*db.x + db.y*db.y + db.z*db.z + db.w*db.w;
}

__global__ __launch_bounds__(DIST_THREADS, 4) void center_dist_kernel(const float* __restrict__ feat,
                                                                      const int* __restrict__ label,
                                                                      const float* __restrict__ centers,
                                                                      const int* __restrict__ count,
                                                                      float* __restrict__ out) {
    __shared__ float wave_part[WAVES_PER_BLOCK];
    const int wave = threadIdx.x >> 6;   // 0..7
    const int lane = threadIdx.x & 63;   // 0..63

    // Wave-uniform sample base, forced into an SGPR: labels/counts become
    // s_loads and the feat/center bases become SGPR pairs (vector loads are
    // then s[base] + shared lane voffset).
    const int b = __builtin_amdgcn_readfirstlane(
        blockIdx.x * SAMPLES_PER_BLOCK + wave * SAMPLES_PER_WAVE);

    const int lab0 = label[b + 0];
    const int lab1 = label[b + 1];
    const int lab2 = label[b + 2];
    const int lab3 = label[b + 3];
    const int cnt0 = count[lab0];
    const int cnt1 = count[lab1];
    const int cnt2 = count[lab2];
    const int cnt3 = count[lab3];

    const vfloat4* f0 = reinterpret_cast<const vfloat4*>(feat + (size_t)(b + 0) * FEATURE_DIM);
    const vfloat4* f1 = reinterpret_cast<const vfloat4*>(feat + (size_t)(b + 1) * FEATURE_DIM);
    const vfloat4* f2 = reinterpret_cast<const vfloat4*>(feat + (size_t)(b + 2) * FEATURE_DIM);
    const vfloat4* f3 = reinterpret_cast<const vfloat4*>(feat + (size_t)(b + 3) * FEATURE_DIM);
    const vfloat4* c0 = reinterpret_cast<const vfloat4*>(centers + (size_t)lab0 * FEATURE_DIM);
    const vfloat4* c1 = reinterpret_cast<const vfloat4*>(centers + (size_t)lab1 * FEATURE_DIM);
    const vfloat4* c2 = reinterpret_cast<const vfloat4*>(centers + (size_t)lab2 * FEATURE_DIM);
    const vfloat4* c3 = reinterpret_cast<const vfloat4*>(centers + (size_t)lab3 * FEATURE_DIM);

    // 16 independent 16B-per-lane coalesced loads in flight.
    vfloat4 fa0 = f0[lane], fb0 = f0[lane + 64];
    vfloat4 fa1 = f1[lane], fb1 = f1[lane + 64];
    vfloat4 fa2 = f2[lane], fb2 = f2[lane + 64];
    vfloat4 fa3 = f3[lane], fb3 = f3[lane + 64];
    vfloat4 ca0 = c0[lane], cb0 = c0[lane + 64];
    vfloat4 ca1 = c1[lane], cb1 = c1[lane + 64];
    vfloat4 ca2 = c2[lane], cb2 = c2[lane + 64];
    vfloat4 ca3 = c3[lane], cb3 = c3[lane + 64];

    float s0 = sq8(fa0, fb0, ca0, cb0);
    float s1 = sq8(fa1, fb1, ca1, cb1);
    float s2 = sq8(fa2, fb2, ca2, cb2);
    float s3 = sq8(fa3, fb3, ca3, cb3);

    // Four interleaved 64-lane butterfly reductions (independent chains).
    #pragma unroll
    for (int off = 32; off > 0; off >>= 1) {
        s0 += __shfl_down(s0, off, 64);
        s1 += __shfl_down(s1, off, 64);
        s2 += __shfl_down(s2, off, 64);
        s3 += __shfl_down(s3, off, 64);
    }

    if (lane == 0) {
        wave_part[wave] = sqrtf(s0) / (float)cnt0
                        + sqrtf(s1) / (float)cnt1
                        + sqrtf(s2) / (float)cnt2
                        + sqrtf(s3) / (float)cnt3;
    }
    __syncthreads();

    if (threadIdx.x == 0) {
        float sum = 0.0f;
        #pragma unroll
        for (int w = 0; w < WAVES_PER_BLOCK; ++w) sum += wave_part[w];
        atomicAdd(out, sum * (1.0f / (float)BATCH));  // 512 atomics total
    }
}

extern "C" void kernel_launch(void* const* d_in, const int* in_sizes, int n_in,
                              void* d_out, int out_size, void* d_ws, size_t ws_size,
                              hipStream_t stream) {
    const float* feat    = (const float*)d_in[0];
    const int*   label   = (const int*)  d_in[1];
    const float* centers = (const float*)d_in[2];
    float*       out     = (float*)d_out;
    int*         count   = (int*)d_ws;

    center_hist_kernel<<<HIST_BLOCKS, 1024, 0, stream>>>(label, count, out);

    center_dist_kernel<<<DIST_BLOCKS, DIST_THREADS, 0, stream>>>(
        feat, label, centers, count, out);
}